// Round 5
// baseline (387.187 us; speedup 1.0000x reference)
//
#include <hip/hip_runtime.h>
#include <math.h>

#define B_ROWS 1024
#define D_EMB  1568
#define H_HEADS 16
#define HSZ    98
#define FF_DIM 6272
#define OUT_DIM 784

typedef unsigned short ushort_t;
typedef __attribute__((ext_vector_type(8))) short short8;
typedef __attribute__((ext_vector_type(4))) float floatx4;

static __device__ __forceinline__ ushort_t f2bf(float f) {
    unsigned int u = __builtin_bit_cast(unsigned int, f);
    u = (u + 0x7fffu + ((u >> 16) & 1u)) >> 16;   // RNE; our values are never NaN
    return (ushort_t)u;
}
static __device__ __forceinline__ float bf2f(ushort_t h) {
    unsigned int u = ((unsigned int)h) << 16;
    return __builtin_bit_cast(float, u);
}

// async 16B global -> LDS. dest = wave-uniform base; HW scatters lane*16.
static __device__ __forceinline__ void load16_to_lds(const void* g, void* l) {
    __builtin_amdgcn_global_load_lds(
        (const __attribute__((address_space(1))) void*)g,
        (__attribute__((address_space(3))) void*)l,
        16, 0, 0);
}

// ---------------- LayerNorm: fp32 in -> bf16 out ----------------
__global__ __launch_bounds__(256) void ln_kernel(const float* __restrict__ x,
                                                 const float* __restrict__ g,
                                                 const float* __restrict__ b,
                                                 ushort_t* __restrict__ out, int D) {
    const int row = blockIdx.x;
    const float* xr = x + (size_t)row * D;
    ushort_t* orow = out + (size_t)row * D;

    float s = 0.f, s2 = 0.f;
    for (int i = threadIdx.x; i < D; i += blockDim.x) {
        float v = xr[i];
        s += v; s2 += v * v;
    }
    #pragma unroll
    for (int off = 32; off > 0; off >>= 1) {
        s  += __shfl_down(s,  off, 64);
        s2 += __shfl_down(s2, off, 64);
    }
    __shared__ float ws_[8], ws2_[8];
    const int wave = threadIdx.x >> 6, lane = threadIdx.x & 63;
    if (lane == 0) { ws_[wave] = s; ws2_[wave] = s2; }
    __syncthreads();
    if (threadIdx.x == 0) {
        float ts = 0.f, ts2 = 0.f;
        for (int i = 0; i < 4; i++) { ts += ws_[i]; ts2 += ws2_[i]; }
        ws_[0] = ts; ws2_[0] = ts2;
    }
    __syncthreads();
    const float mean = ws_[0] / (float)D;
    const float var  = ws2_[0] / (float)D - mean * mean;
    const float inv  = rsqrtf(var + 1e-5f);
    for (int i = threadIdx.x; i < D; i += blockDim.x)
        orow[i] = f2bf((xr[i] - mean) * inv * g[i] + b[i]);
}

// ------- weight transpose+convert: fp32 [K][N] -> bf16 [Npad][K], zero rows N..Npad -------
// 64x64 tile: float coalesced reads (256 B/row), ushort4 writes (8 B/lane).
__global__ __launch_bounds__(256) void transpose_plain(const float* __restrict__ src,
                                                       ushort_t* __restrict__ dst,
                                                       int K, int N, int Npad) {
    __shared__ float t[64][65];
    const int n0 = blockIdx.x * 64, k0 = blockIdx.y * 64;
    const int tid = threadIdx.x;
    const int tx = tid & 63, ty = tid >> 6;     // tx = n_local, ty = k phase (0..3)
    #pragma unroll
    for (int r = 0; r < 16; r++) {
        const int kl = ty + r * 4;
        const int k = k0 + kl, n = n0 + tx;
        t[tx][kl] = (k < K && n < N) ? src[(size_t)k * N + n] : 0.f;
    }
    __syncthreads();
    #pragma unroll
    for (int w = 0; w < 4; w++) {
        const int nl = (tid >> 4) + w * 16;     // 0..63
        const int kc = (tid & 15) * 4;          // 0..60
        const int n = n0 + nl, k = k0 + kc;
        if (n < Npad && k < K) {                // K%4==0 so whole quad in-bounds
            ushort4 uv;
            uv.x = f2bf(t[nl][kc + 0]);
            uv.y = f2bf(t[nl][kc + 1]);
            uv.z = f2bf(t[nl][kc + 2]);
            uv.w = f2bf(t[nl][kc + 3]);
            *(ushort4*)(dst + (size_t)n * K + k) = uv;
        }
    }
}

// QKV: Wq/Wk/Wv (H, K, 98) fp32 -> dst bf16 [4736][K], row n = which*1568 + head*98 + e
// (rows 4704..4735 unwritten poison: GEMM masks those columns on store; bf16 0xAAAA≈-3e-13)
__global__ __launch_bounds__(256) void transpose_qkv(const float* __restrict__ Wq,
                                                     const float* __restrict__ Wk,
                                                     const float* __restrict__ Wv,
                                                     ushort_t* __restrict__ dst, int K) {
    __shared__ float t[32][33];
    const int which = blockIdx.z >> 4;
    const int head  = blockIdx.z & 15;
    const float* src = (which == 0) ? Wq : (which == 1) ? Wk : Wv;
    src += (size_t)head * K * HSZ;
    const int e0 = blockIdx.x * 32, k0 = blockIdx.y * 32;
    const int tx = threadIdx.x, ty = threadIdx.y;
    #pragma unroll
    for (int i = 0; i < 4; i++) {
        const int k = k0 + ty + i * 8, e = e0 + tx;
        t[ty + i * 8][tx] = (e < HSZ && k < K) ? src[(size_t)k * HSZ + e] : 0.f;
    }
    __syncthreads();
    const int nbase = which * D_EMB + head * HSZ;
    #pragma unroll
    for (int i = 0; i < 4; i++) {
        const int e = e0 + ty + i * 8, k = k0 + tx;
        if (e < HSZ && k < K) dst[(size_t)(nbase + e) * K + k] = f2bf(t[tx][ty + i * 8]);
    }
}

// -------- bf16 MFMA GEMM, 128x128x32 tile, split-K, bf16 partial planes --------
// A: bf16 [1024][K] row-major.  Bt: bf16 [Npad][K] (k-major).
// Grid: x = m-tile (8, fastest: blocks sharing a B-tile co-dispatch), y = n-tile, z = K-split.
// P[z] = bf16 plane [1024][N]. 4 waves 2x2, 16 MFMA/wave/iter (max MFMA per barrier drain).
__global__ __launch_bounds__(256) void gemm_bf16(const ushort_t* __restrict__ A,
                                                 const ushort_t* __restrict__ Bt,
                                                 ushort_t* __restrict__ P,
                                                 int N, int K, int nkTot) {
    __shared__ __align__(16) ushort_t As[128 * 32];
    __shared__ __align__(16) ushort_t Bs[128 * 32];

    const int tid  = threadIdx.x;
    const int wave = tid >> 6, lane = tid & 63;
    const int quad = lane >> 4, l16 = lane & 15;
    const int m0 = blockIdx.x * 128;
    const int n0 = blockIdx.y * 128;
    const int z = blockIdx.z, Z = gridDim.z;
    const int it0 = (int)((long long)nkTot * z / Z);
    const int it1 = (int)((long long)nkTot * (z + 1) / Z);

    const int srow = lane >> 2;          // 0..15
    const int scol = (lane & 3) << 3;    // 0,8,16,24 (k elems)
    const int wm = wave & 1, wn = wave >> 1;

    floatx4 acc[4][4] = {};

    for (int it = it0; it < it1; ++it) {
        const int k0 = it << 5;
        #pragma unroll
        for (int c = 0; c < 2; ++c) {
            const int chunk = wave * 2 + c;          // wave-uniform
            const int row = chunk * 16 + srow;
            load16_to_lds(A  + (size_t)(m0 + row) * K + k0 + scol, &As[chunk * 512]);
            load16_to_lds(Bt + (size_t)(n0 + row) * K + k0 + scol, &Bs[chunk * 512]);
        }
        __syncthreads();

        short8 af[4], bfr[4];
        #pragma unroll
        for (int i = 0; i < 4; i++)
            af[i] = *(const short8*)&As[(wm * 64 + i * 16 + l16) * 32 + quad * 8];
        #pragma unroll
        for (int j = 0; j < 4; j++)
            bfr[j] = *(const short8*)&Bs[(wn * 64 + j * 16 + l16) * 32 + quad * 8];
        #pragma unroll
        for (int i = 0; i < 4; i++)
            #pragma unroll
            for (int j = 0; j < 4; j++)
                acc[i][j] = __builtin_amdgcn_mfma_f32_16x16x32_bf16(af[i], bfr[j], acc[i][j], 0, 0, 0);
        __syncthreads();
    }

    ushort_t* Pz = P + (size_t)z * B_ROWS * N;
    #pragma unroll
    for (int i = 0; i < 4; i++) {
        const int rbase = m0 + wm * 64 + i * 16 + quad * 4;
        #pragma unroll
        for (int j = 0; j < 4; j++) {
            const int col = n0 + wn * 64 + j * 16 + l16;
            if (col < N) {
                #pragma unroll
                for (int r = 0; r < 4; r++)
                    Pz[(size_t)(rbase + r) * N + col] = f2bf(acc[i][j][r]);
            }
        }
    }
}

// -------- fused: Z-plane combine + bias + LayerNorm -> bf16 (one block per row) --------
template <int Z>
__global__ __launch_bounds__(256) void combine_ln_kernel(const ushort_t* __restrict__ P,
                                                         const float* __restrict__ bias,
                                                         const float* __restrict__ g,
                                                         const float* __restrict__ b,
                                                         ushort_t* __restrict__ out, int N) {
    __shared__ float t[D_EMB];
    __shared__ float ws_[8], ws2_[8];
    const int row = blockIdx.x;
    const size_t plane = (size_t)B_ROWS * N;
    const ushort_t* Pr = P + (size_t)row * N;
    const int half = N >> 1;

    float s = 0.f, s2 = 0.f;
    for (int i = threadIdx.x; i < half; i += blockDim.x) {
        float v0 = bias[2 * i], v1 = bias[2 * i + 1];
        #pragma unroll
        for (int zz = 0; zz < Z; zz++) {
            const ushort2 u = *(const ushort2*)(Pr + (size_t)zz * plane + 2 * i);
            v0 += bf2f(u.x); v1 += bf2f(u.y);
        }
        t[2 * i] = v0; t[2 * i + 1] = v1;
        s += v0 + v1; s2 += v0 * v0 + v1 * v1;
    }
    #pragma unroll
    for (int off = 32; off > 0; off >>= 1) {
        s  += __shfl_down(s,  off, 64);
        s2 += __shfl_down(s2, off, 64);
    }
    const int wave = threadIdx.x >> 6, lane = threadIdx.x & 63;
    if (lane == 0) { ws_[wave] = s; ws2_[wave] = s2; }
    __syncthreads();
    if (threadIdx.x == 0) {
        float ts = 0.f, ts2 = 0.f;
        for (int i = 0; i < 4; i++) { ts += ws_[i]; ts2 += ws2_[i]; }
        ws_[0] = ts; ws2_[0] = ts2;
    }
    __syncthreads();
    const float mean = ws_[0] / (float)N;
    const float var  = ws2_[0] / (float)N - mean * mean;
    const float inv  = rsqrtf(var + 1e-5f);
    ushort_t* orow = out + (size_t)row * N;
    for (int i = threadIdx.x; i < N; i += blockDim.x)
        orow[i] = f2bf((t[i] - mean) * inv * g[i] + b[i]);
}

// -------- combine Z=2 + bias + GELU, in-place into plane 0 (thread-local addresses) --------
__global__ __launch_bounds__(256) void combine_gelu_kernel(ushort_t* __restrict__ P,
                                                           const float* __restrict__ bias,
                                                           int N) {
    const int c4 = (blockIdx.x * 256 + threadIdx.x) * 4;
    if (c4 >= N) return;
    const int row = blockIdx.y;
    const size_t plane = (size_t)B_ROWS * N;
    const size_t off = (size_t)row * N + c4;
    const ushort4 a = *(const ushort4*)(P + off);
    const ushort4 c = *(const ushort4*)(P + plane + off);
    float v[4] = { bf2f(a.x) + bf2f(c.x) + bias[c4 + 0],
                   bf2f(a.y) + bf2f(c.y) + bias[c4 + 1],
                   bf2f(a.z) + bf2f(c.z) + bias[c4 + 2],
                   bf2f(a.w) + bf2f(c.w) + bias[c4 + 3] };
    ushort4 o;
    #pragma unroll
    for (int j = 0; j < 4; j++)
        v[j] = 0.5f * v[j] * (1.f + erff(v[j] * 0.70710678118654752f));
    o.x = f2bf(v[0]); o.y = f2bf(v[1]); o.z = f2bf(v[2]); o.w = f2bf(v[3]);
    *(ushort4*)(P + off) = o;
}

// -------- combine Z planes + bias -> fp32 out --------
template <int Z>
__global__ __launch_bounds__(256) void combine_out_kernel(const ushort_t* __restrict__ P,
                                                          const float* __restrict__ bias,
                                                          float* __restrict__ out, int N) {
    const int c2 = blockIdx.x * 256 + threadIdx.x;
    if (c2 >= (N >> 1)) return;
    const int row = blockIdx.y;
    const size_t plane = (size_t)B_ROWS * N;
    const size_t off = (size_t)row * N + 2 * c2;
    float v0 = bias[2 * c2], v1 = bias[2 * c2 + 1];
    #pragma unroll
    for (int zz = 0; zz < Z; zz++) {
        const ushort2 u = *(const ushort2*)(P + (size_t)zz * plane + off);
        v0 += bf2f(u.x); v1 += bf2f(u.y);
    }
    out[off] = v0; out[off + 1] = v1;
}

// ---------------- rank-1 pseudo-attention (sums the 2 QKV partial planes inline) ----------------
// P: 2 bf16 planes [1024][4704]: q at col h*98+e, k at +1568, v at +3136. out bf16 [B][1568].
__global__ __launch_bounds__(128) void attn_kernel(const ushort_t* __restrict__ P,
                                                   ushort_t* __restrict__ out) {
    const int bh = blockIdx.x;
    const int b = bh >> 4, h = bh & 15;
    const size_t base = (size_t)b * 4704 + h * HSZ;
    const size_t plane = (size_t)B_ROWS * 4704;

    __shared__ float ks[HSZ], vs[HSZ];
    __shared__ float kmax_s, kmin_s;

    const int t = threadIdx.x;
    if (t < HSZ) {
        ks[t] = bf2f(P[base + 1568 + t]) + bf2f(P[plane + base + 1568 + t]);
        vs[t] = bf2f(P[base + 3136 + t]) + bf2f(P[plane + base + 3136 + t]);
    }
    __syncthreads();
    if (t == 0) {
        float mx = -1e30f, mn = 1e30f;
        for (int j = 0; j < HSZ; j++) { mx = fmaxf(mx, ks[j]); mn = fminf(mn, ks[j]); }
        kmax_s = mx; kmin_s = mn;
    }
    __syncthreads();
    if (t < HSZ) {
        const float q = bf2f(P[base + t]) + bf2f(P[plane + base + t]);
        const float ti = q * 0.025253813613805268f;  // 1568^-0.5
        const float m = (ti >= 0.f) ? ti * kmax_s : ti * kmin_s;
        float s = 0.f, acc = 0.f;
        for (int j = 0; j < HSZ; j++) {
            const float e = __expf(ti * ks[j] - m);
            s += e; acc += e * vs[j];
        }
        out[(size_t)b * D_EMB + h * HSZ + t] = f2bf(acc / s);
    }
}

// ---------------- launch ----------------
// Workspace map (peak exactly 51,380,224 B = R1's proven-safe footprint):
//   A  [0, 20,070,400):           Wot [0, 5,218,304) + Wqkv_t [5,218,304, 20,070,400)
//                                 -> W1t [0, 19,668,992) after Wo GEMM
//                                 -> W2t [0, 11,239,424) after W1 GEMM
//   Bp [20,070,400, 48,168,960):  P_qkv Z=2 (19.27 MB) -> P_Wo Z=6 (19.27 MB)
//                                 -> P_W1 Z=2 (25.69 MB) -> ff1 in-place over P_W1 plane0
//                                    (12.85 MB) + P_W2 Z=9 at +12,845,056 (14.45 MB)
//   C  [48,168,960, 51,380,224):  h_bf 3.21 MB (LN1 -> attn out -> LN2 out, serial)
extern "C" void kernel_launch(void* const* d_in, const int* in_sizes, int n_in,
                              void* d_out, int out_size, void* d_ws, size_t ws_size,
                              hipStream_t stream) {
    const float* x   = (const float*)d_in[0];
    const float* Wq  = (const float*)d_in[1];
    const float* Wk  = (const float*)d_in[2];
    const float* Wv  = (const float*)d_in[3];
    const float* Wo  = (const float*)d_in[4];
    const float* bo  = (const float*)d_in[5];
    const float* g1  = (const float*)d_in[6];
    const float* b1  = (const float*)d_in[7];
    const float* g2  = (const float*)d_in[8];
    const float* b2  = (const float*)d_in[9];
    const float* W1  = (const float*)d_in[10];
    const float* b1f = (const float*)d_in[11];
    const float* W2  = (const float*)d_in[12];
    const float* b2f = (const float*)d_in[13];
    float* out = (float*)d_out;

    char* w = (char*)d_ws;
    ushort_t* Wot    = (ushort_t*)(w);
    ushort_t* Wqkvt  = (ushort_t*)(w + 5218304);
    ushort_t* W1t    = (ushort_t*)(w);
    ushort_t* W2t    = (ushort_t*)(w);
    ushort_t* Pb     = (ushort_t*)(w + 20070400);     // partial planes region
    ushort_t* ff1    = Pb;                             // in-place over P_W1 plane 0
    ushort_t* Pw2    = (ushort_t*)(w + 32915456);     // W2 partials Z=9
    ushort_t* h_bf   = (ushort_t*)(w + 48168960);     // serial LN1/attn/LN2 buffer

    // 1. LN1 -> h_bf
    ln_kernel<<<B_ROWS, 256, 0, stream>>>(x, g1, b1, h_bf, D_EMB);

    // 2. weight prep for stage 1: Wqkv^T and Wo^T
    transpose_qkv<<<dim3(4, 49, 48), dim3(32, 8), 0, stream>>>(Wq, Wk, Wv, Wqkvt, D_EMB);
    transpose_plain<<<dim3(26, 25), 256, 0, stream>>>(Wo, Wot, D_EMB, D_EMB, 1664);

    // 3. QKV GEMM: N=4704, K=1568, Z=2, grid 8x37x2 = 592 blocks
    gemm_bf16<<<dim3(8, 37, 2), 256, 0, stream>>>(h_bf, Wqkvt, Pb, 4704, D_EMB, 49);

    // 4. attention (sums 2 planes) -> h_bf
    attn_kernel<<<B_ROWS * H_HEADS, 128, 0, stream>>>(Pb, h_bf);

    // 5. Wo GEMM: N=1568, Z=6, grid 8x13x6 = 624 blocks
    gemm_bf16<<<dim3(8, 13, 6), 256, 0, stream>>>(h_bf, Wot, Pb, D_EMB, D_EMB, 49);

    // 6. W1^T (after Wo GEMM: A region free)
    transpose_plain<<<dim3(98, 25), 256, 0, stream>>>(W1, W1t, D_EMB, FF_DIM, FF_DIM);

    // 7. combine+bias+LN2 -> h_bf
    combine_ln_kernel<6><<<B_ROWS, 256, 0, stream>>>(Pb, bo, g2, b2, h_bf, D_EMB);

    // 8. W1 GEMM: N=6272, K=1568, Z=2, grid 8x49x2 = 784 blocks
    gemm_bf16<<<dim3(8, 49, 2), 256, 0, stream>>>(h_bf, W1t, Pb, FF_DIM, D_EMB, 49);

    // 9. W2^T (after W1 GEMM)
    transpose_plain<<<dim3(14, 98), 256, 0, stream>>>(W2, W2t, FF_DIM, OUT_DIM, 896);

    // 10. combine Z=2 + bias + GELU -> ff1 (in-place plane 0)
    combine_gelu_kernel<<<dim3(7, B_ROWS), 256, 0, stream>>>(Pb, b1f, FF_DIM);

    // 11. W2 GEMM: N=784, K=6272, Z=9, grid 8x7x9 = 504 blocks
    gemm_bf16<<<dim3(8, 7, 9), 256, 0, stream>>>(ff1, W2t, Pw2, OUT_DIM, FF_DIM, 196);

    // 12. combine Z=9 + bias -> out (fp32)
    combine_out_kernel<9><<<dim3(2, B_ROWS), 256, 0, stream>>>(Pw2, b2f, out, OUT_DIM);
}

// Round 6
// 372.587 us; speedup vs baseline: 1.0392x; 1.0392x over previous
//
#include <hip/hip_runtime.h>
#include <math.h>

#define B_ROWS 1024
#define D_EMB  1568
#define KP     1600      // D_EMB padded to a multiple of 64 (BK)
#define H_HEADS 16
#define HSZ    98
#define FF_DIM 6272
#define OUT_DIM 784

typedef unsigned short ushort_t;
typedef __attribute__((ext_vector_type(8))) short short8;
typedef __attribute__((ext_vector_type(4))) float floatx4;

static __device__ __forceinline__ ushort_t f2bf(float f) {
    unsigned int u = __builtin_bit_cast(unsigned int, f);
    u = (u + 0x7fffu + ((u >> 16) & 1u)) >> 16;   // RNE; our values are never NaN
    return (ushort_t)u;
}
static __device__ __forceinline__ float bf2f(ushort_t h) {
    unsigned int u = ((unsigned int)h) << 16;
    return __builtin_bit_cast(float, u);
}

// async 16B global -> LDS. dest = wave-uniform base; HW scatters lane*16.
static __device__ __forceinline__ void load16_to_lds(const void* g, void* l) {
    __builtin_amdgcn_global_load_lds(
        (const __attribute__((address_space(1))) void*)g,
        (__attribute__((address_space(3))) void*)l,
        16, 0, 0);
}

// ---------------- LayerNorm: fp32 in -> bf16 out (cols D..DPAD zeroed) ----------------
__global__ __launch_bounds__(256) void ln_kernel(const float* __restrict__ x,
                                                 const float* __restrict__ g,
                                                 const float* __restrict__ b,
                                                 ushort_t* __restrict__ out,
                                                 int D, int DPAD) {
    const int row = blockIdx.x;
    const float* xr = x + (size_t)row * D;
    ushort_t* orow = out + (size_t)row * DPAD;

    float s = 0.f, s2 = 0.f;
    for (int i = threadIdx.x; i < D; i += blockDim.x) {
        float v = xr[i];
        s += v; s2 += v * v;
    }
    #pragma unroll
    for (int off = 32; off > 0; off >>= 1) {
        s  += __shfl_down(s,  off, 64);
        s2 += __shfl_down(s2, off, 64);
    }
    __shared__ float ws_[8], ws2_[8];
    const int wave = threadIdx.x >> 6, lane = threadIdx.x & 63;
    if (lane == 0) { ws_[wave] = s; ws2_[wave] = s2; }
    __syncthreads();
    if (threadIdx.x == 0) {
        float ts = 0.f, ts2 = 0.f;
        for (int i = 0; i < 4; i++) { ts += ws_[i]; ts2 += ws2_[i]; }
        ws_[0] = ts; ws2_[0] = ts2;
    }
    __syncthreads();
    const float mean = ws_[0] / (float)D;
    const float var  = ws2_[0] / (float)D - mean * mean;
    const float inv  = rsqrtf(var + 1e-5f);
    for (int i = threadIdx.x; i < DPAD; i += blockDim.x)
        orow[i] = (i < D) ? f2bf((xr[i] - mean) * inv * g[i] + b[i]) : (ushort_t)0;
}

// ------- weight transpose+convert: fp32 [K][N] -> bf16 [Npad][dstride] -------
// 64x64 tile: float coalesced reads, ushort4 writes. k-pad cols (K..dstride) left
// as-is (finite poison; A-side zeros make the products exact zero).
__global__ __launch_bounds__(256) void transpose_plain(const float* __restrict__ src,
                                                       ushort_t* __restrict__ dst,
                                                       int K, int N, int Npad, int dstride) {
    __shared__ float t[64][65];
    const int n0 = blockIdx.x * 64, k0 = blockIdx.y * 64;
    const int tid = threadIdx.x;
    const int tx = tid & 63, ty = tid >> 6;
    #pragma unroll
    for (int r = 0; r < 16; r++) {
        const int kl = ty + r * 4;
        const int k = k0 + kl, n = n0 + tx;
        t[tx][kl] = (k < K && n < N) ? src[(size_t)k * N + n] : 0.f;
    }
    __syncthreads();
    #pragma unroll
    for (int w = 0; w < 4; w++) {
        const int nl = (tid >> 4) + w * 16;
        const int kc = (tid & 15) * 4;
        const int n = n0 + nl, k = k0 + kc;
        if (n < Npad && k < K) {                // K%4==0: whole quad in-bounds
            ushort4 uv;
            uv.x = f2bf(t[nl][kc + 0]);
            uv.y = f2bf(t[nl][kc + 1]);
            uv.z = f2bf(t[nl][kc + 2]);
            uv.w = f2bf(t[nl][kc + 3]);
            *(ushort4*)(dst + (size_t)n * dstride + k) = uv;
        }
    }
}

// QKV: Wq/Wk/Wv (H, K, 98) fp32 -> dst bf16 [4736][KP], row n = which*1568 + head*98 + e
// (rows 4704..4735 unwritten poison: GEMM masks those columns on store)
__global__ __launch_bounds__(256) void transpose_qkv(const float* __restrict__ Wq,
                                                     const float* __restrict__ Wk,
                                                     const float* __restrict__ Wv,
                                                     ushort_t* __restrict__ dst, int K) {
    __shared__ float t[32][33];
    const int which = blockIdx.z >> 4;
    const int head  = blockIdx.z & 15;
    const float* src = (which == 0) ? Wq : (which == 1) ? Wk : Wv;
    src += (size_t)head * K * HSZ;
    const int e0 = blockIdx.x * 32, k0 = blockIdx.y * 32;
    const int tx = threadIdx.x, ty = threadIdx.y;
    #pragma unroll
    for (int i = 0; i < 4; i++) {
        const int k = k0 + ty + i * 8, e = e0 + tx;
        t[ty + i * 8][tx] = (e < HSZ && k < K) ? src[(size_t)k * HSZ + e] : 0.f;
    }
    __syncthreads();
    const int nbase = which * D_EMB + head * HSZ;
    #pragma unroll
    for (int i = 0; i < 4; i++) {
        const int e = e0 + ty + i * 8, k = k0 + tx;
        if (e < HSZ && k < K) dst[(size_t)(nbase + e) * KP + k] = f2bf(t[tx][ty + i * 8]);
    }
}

// -------- bf16 MFMA GEMM, 128x128 tile, BK=64 (two 32-k panels per barrier) --------
// A: bf16 [1024][Kstride] row-major (k-pad zeroed).  Bt: bf16 [Npad][Kstride] k-major.
// Grid: x = m-tile (8), y = n-tile, z = K-split. P[z] = bf16 plane [1024][N].
// LDS: two 8KB panels per matrix, each panel row-stride 64B (R5-proven addressing).
// Per barrier pair: 2 x 16 MFMA per wave (halves barrier drains vs BK=32).
__global__ __launch_bounds__(256) void gemm_bf16(const ushort_t* __restrict__ A,
                                                 const ushort_t* __restrict__ Bt,
                                                 ushort_t* __restrict__ P,
                                                 int N, int Kstride, int nkTot) {
    __shared__ __align__(16) ushort_t As[2 * 128 * 32];   // [ks][row][32]
    __shared__ __align__(16) ushort_t Bs[2 * 128 * 32];

    const int tid  = threadIdx.x;
    const int wave = tid >> 6, lane = tid & 63;
    const int quad = lane >> 4, l16 = lane & 15;
    const int m0 = blockIdx.x * 128;
    const int n0 = blockIdx.y * 128;
    const int z = blockIdx.z, Z = gridDim.z;
    const int it0 = (int)((long long)nkTot * z / Z);
    const int it1 = (int)((long long)nkTot * (z + 1) / Z);

    const int srow = lane >> 2;          // 0..15 (row within 16-row chunk)
    const int scol = (lane & 3) << 3;    // 0,8,16,24 (k elems within 32-k panel)
    const int wm = wave & 1, wn = wave >> 1;

    floatx4 acc[4][4] = {};

    for (int it = it0; it < it1; ++it) {
        const int k0 = it << 6;
        #pragma unroll
        for (int c = 0; c < 2; ++c) {
            const int rg = wave * 2 + c;             // rowgroup 0..7, wave-uniform
            const int row = rg * 16 + srow;
            #pragma unroll
            for (int ks = 0; ks < 2; ++ks) {
                load16_to_lds(A  + (size_t)(m0 + row) * Kstride + k0 + ks * 32 + scol,
                              &As[ks * 4096 + rg * 512]);
                load16_to_lds(Bt + (size_t)(n0 + row) * Kstride + k0 + ks * 32 + scol,
                              &Bs[ks * 4096 + rg * 512]);
            }
        }
        __syncthreads();

        #pragma unroll
        for (int ks = 0; ks < 2; ++ks) {
            short8 af[4], bfr[4];
            #pragma unroll
            for (int i = 0; i < 4; i++)
                af[i] = *(const short8*)&As[ks * 4096 + (wm * 64 + i * 16 + l16) * 32 + quad * 8];
            #pragma unroll
            for (int j = 0; j < 4; j++)
                bfr[j] = *(const short8*)&Bs[ks * 4096 + (wn * 64 + j * 16 + l16) * 32 + quad * 8];
            #pragma unroll
            for (int i = 0; i < 4; i++)
                #pragma unroll
                for (int j = 0; j < 4; j++)
                    acc[i][j] = __builtin_amdgcn_mfma_f32_16x16x32_bf16(af[i], bfr[j], acc[i][j], 0, 0, 0);
        }
        __syncthreads();
    }

    ushort_t* Pz = P + (size_t)z * B_ROWS * N;
    #pragma unroll
    for (int i = 0; i < 4; i++) {
        const int rbase = m0 + wm * 64 + i * 16 + quad * 4;
        #pragma unroll
        for (int j = 0; j < 4; j++) {
            const int col = n0 + wn * 64 + j * 16 + l16;
            if (col < N) {
                #pragma unroll
                for (int r = 0; r < 4; r++)
                    Pz[(size_t)(rbase + r) * N + col] = f2bf(acc[i][j][r]);
            }
        }
    }
}

// -------- fused: Z-plane combine + bias + LayerNorm -> bf16 [1024][NPAD], pad zeroed --------
template <int Z>
__global__ __launch_bounds__(256) void combine_ln_kernel(const ushort_t* __restrict__ P,
                                                         const float* __restrict__ bias,
                                                         const float* __restrict__ g,
                                                         const float* __restrict__ b,
                                                         ushort_t* __restrict__ out,
                                                         int N, int NPAD) {
    __shared__ float t[D_EMB];
    __shared__ float ws_[8], ws2_[8];
    const int row = blockIdx.x;
    const size_t plane = (size_t)B_ROWS * N;
    const ushort_t* Pr = P + (size_t)row * N;
    const int half = N >> 1;

    float s = 0.f, s2 = 0.f;
    for (int i = threadIdx.x; i < half; i += blockDim.x) {
        float v0 = bias[2 * i], v1 = bias[2 * i + 1];
        #pragma unroll
        for (int zz = 0; zz < Z; zz++) {
            const ushort2 u = *(const ushort2*)(Pr + (size_t)zz * plane + 2 * i);
            v0 += bf2f(u.x); v1 += bf2f(u.y);
        }
        t[2 * i] = v0; t[2 * i + 1] = v1;
        s += v0 + v1; s2 += v0 * v0 + v1 * v1;
    }
    #pragma unroll
    for (int off = 32; off > 0; off >>= 1) {
        s  += __shfl_down(s,  off, 64);
        s2 += __shfl_down(s2, off, 64);
    }
    const int wave = threadIdx.x >> 6, lane = threadIdx.x & 63;
    if (lane == 0) { ws_[wave] = s; ws2_[wave] = s2; }
    __syncthreads();
    if (threadIdx.x == 0) {
        float ts = 0.f, ts2 = 0.f;
        for (int i = 0; i < 4; i++) { ts += ws_[i]; ts2 += ws2_[i]; }
        ws_[0] = ts; ws2_[0] = ts2;
    }
    __syncthreads();
    const float mean = ws_[0] / (float)N;
    const float var  = ws2_[0] / (float)N - mean * mean;
    const float inv  = rsqrtf(var + 1e-5f);
    ushort_t* orow = out + (size_t)row * NPAD;
    for (int i = threadIdx.x; i < NPAD; i += blockDim.x)
        orow[i] = (i < N) ? f2bf((t[i] - mean) * inv * g[i] + b[i]) : (ushort_t)0;
}

// -------- combine Z=2 + bias + GELU, in-place into plane 0 --------
__global__ __launch_bounds__(256) void combine_gelu_kernel(ushort_t* __restrict__ P,
                                                           const float* __restrict__ bias,
                                                           int N) {
    const int c4 = (blockIdx.x * 256 + threadIdx.x) * 4;
    if (c4 >= N) return;
    const int row = blockIdx.y;
    const size_t plane = (size_t)B_ROWS * N;
    const size_t off = (size_t)row * N + c4;
    const ushort4 a = *(const ushort4*)(P + off);
    const ushort4 c = *(const ushort4*)(P + plane + off);
    float v[4] = { bf2f(a.x) + bf2f(c.x) + bias[c4 + 0],
                   bf2f(a.y) + bf2f(c.y) + bias[c4 + 1],
                   bf2f(a.z) + bf2f(c.z) + bias[c4 + 2],
                   bf2f(a.w) + bf2f(c.w) + bias[c4 + 3] };
    ushort4 o;
    #pragma unroll
    for (int j = 0; j < 4; j++)
        v[j] = 0.5f * v[j] * (1.f + erff(v[j] * 0.70710678118654752f));
    o.x = f2bf(v[0]); o.y = f2bf(v[1]); o.z = f2bf(v[2]); o.w = f2bf(v[3]);
    *(ushort4*)(P + off) = o;
}

// -------- combine Z planes + bias -> fp32 out --------
template <int Z>
__global__ __launch_bounds__(256) void combine_out_kernel(const ushort_t* __restrict__ P,
                                                          const float* __restrict__ bias,
                                                          float* __restrict__ out, int N) {
    const int c2 = blockIdx.x * 256 + threadIdx.x;
    if (c2 >= (N >> 1)) return;
    const int row = blockIdx.y;
    const size_t plane = (size_t)B_ROWS * N;
    const size_t off = (size_t)row * N + 2 * c2;
    float v0 = bias[2 * c2], v1 = bias[2 * c2 + 1];
    #pragma unroll
    for (int zz = 0; zz < Z; zz++) {
        const ushort2 u = *(const ushort2*)(P + (size_t)zz * plane + off);
        v0 += bf2f(u.x); v1 += bf2f(u.y);
    }
    out[off] = v0; out[off + 1] = v1;
}

// ---------------- rank-1 pseudo-attention (sums the 2 QKV partial planes inline) ----------------
// P: 2 bf16 planes [1024][4704]: q at col h*98+e, k at +1568, v at +3136. out bf16 [1024][KP].
__global__ __launch_bounds__(128) void attn_kernel(const ushort_t* __restrict__ P,
                                                   ushort_t* __restrict__ out) {
    const int bh = blockIdx.x;
    const int b = bh >> 4, h = bh & 15;
    const size_t base = (size_t)b * 4704 + h * HSZ;
    const size_t plane = (size_t)B_ROWS * 4704;

    __shared__ float ks[HSZ], vs[HSZ];
    __shared__ float kmax_s, kmin_s;

    const int t = threadIdx.x;
    if (t < HSZ) {
        ks[t] = bf2f(P[base + 1568 + t]) + bf2f(P[plane + base + 1568 + t]);
        vs[t] = bf2f(P[base + 3136 + t]) + bf2f(P[plane + base + 3136 + t]);
    }
    __syncthreads();
    if (t == 0) {
        float mx = -1e30f, mn = 1e30f;
        for (int j = 0; j < HSZ; j++) { mx = fmaxf(mx, ks[j]); mn = fminf(mn, ks[j]); }
        kmax_s = mx; kmin_s = mn;
    }
    __syncthreads();
    if (t < HSZ) {
        const float q = bf2f(P[base + t]) + bf2f(P[plane + base + t]);
        const float ti = q * 0.025253813613805268f;  // 1568^-0.5
        const float m = (ti >= 0.f) ? ti * kmax_s : ti * kmin_s;
        float s = 0.f, acc = 0.f;
        for (int j = 0; j < HSZ; j++) {
            const float e = __expf(ti * ks[j] - m);
            s += e; acc += e * vs[j];
        }
        out[(size_t)b * KP + h * HSZ + t] = f2bf(acc / s);
    }
}

// ---------------- launch ----------------
// Workspace map (peak 51,052,544 B <= 51,380,224 proven-safe). KP=1600 k-padding.
//   A [0, 20,480,000):  qkvt [0,15,155,200) + Wot [15,155,200,20,480,000)
//                       -> W1t [0,20,070,400) after Wo GEMM
//                       -> W2t [0,11,239,424) after W1 GEMM
//   P [20,480,000, ...): P_qkv Z=2 (19.27MB) -> P_Wo Z=6 (19.27MB)
//                       -> P_W1 Z=2 [20,480,000,46,170,112); ff1 = GELU in-place plane0
//                          [20,480,000,33,325,056); P_W2 Z=9 [33,325,056,47,775,744)
//   C [47,775,744, 51,052,544): h_bf [1024][1600] bf16 (LN1 -> attn -> LN2, serial)
extern "C" void kernel_launch(void* const* d_in, const int* in_sizes, int n_in,
                              void* d_out, int out_size, void* d_ws, size_t ws_size,
                              hipStream_t stream) {
    const float* x   = (const float*)d_in[0];
    const float* Wq  = (const float*)d_in[1];
    const float* Wk  = (const float*)d_in[2];
    const float* Wv  = (const float*)d_in[3];
    const float* Wo  = (const float*)d_in[4];
    const float* bo  = (const float*)d_in[5];
    const float* g1  = (const float*)d_in[6];
    const float* b1  = (const float*)d_in[7];
    const float* g2  = (const float*)d_in[8];
    const float* b2  = (const float*)d_in[9];
    const float* W1  = (const float*)d_in[10];
    const float* b1f = (const float*)d_in[11];
    const float* W2  = (const float*)d_in[12];
    const float* b2f = (const float*)d_in[13];
    float* out = (float*)d_out;

    char* w = (char*)d_ws;
    ushort_t* qkvt = (ushort_t*)(w);
    ushort_t* Wot  = (ushort_t*)(w + 15155200);
    ushort_t* W1t  = (ushort_t*)(w);
    ushort_t* W2t  = (ushort_t*)(w);
    ushort_t* Pb   = (ushort_t*)(w + 20480000);     // partial-plane region
    ushort_t* ff1  = Pb;                            // GELU in-place over P_W1 plane 0
    ushort_t* Pw2  = (ushort_t*)(w + 33325056);     // W2 partials Z=9
    ushort_t* h_bf = (ushort_t*)(w + 47775744);     // serial LN1/attn/LN2 buffer [1024][KP]

    // 1. LN1 -> h_bf (pad cols zeroed)
    ln_kernel<<<B_ROWS, 256, 0, stream>>>(x, g1, b1, h_bf, D_EMB, KP);

    // 2. weight prep stage 1: Wqkv^T [4736][KP], Wo^T [1664][KP]
    transpose_qkv<<<dim3(4, 49, 48), dim3(32, 8), 0, stream>>>(Wq, Wk, Wv, qkvt, D_EMB);
    transpose_plain<<<dim3(26, 25), 256, 0, stream>>>(Wo, Wot, D_EMB, D_EMB, 1664, KP);

    // 3. QKV GEMM: N=4704, Z=2, grid 8x37x2 = 592 blocks, 12-13 iters/block
    gemm_bf16<<<dim3(8, 37, 2), 256, 0, stream>>>(h_bf, qkvt, Pb, 4704, KP, 25);

    // 4. attention (sums 2 planes) -> h_bf
    attn_kernel<<<B_ROWS * H_HEADS, 128, 0, stream>>>(Pb, h_bf);

    // 5. Wo GEMM: N=1568, Z=6, grid 8x13x6 = 624 blocks
    gemm_bf16<<<dim3(8, 13, 6), 256, 0, stream>>>(h_bf, Wot, Pb, D_EMB, KP, 25);

    // 6. W1^T [6272][KP] (region A free after Wo GEMM)
    transpose_plain<<<dim3(98, 25), 256, 0, stream>>>(W1, W1t, D_EMB, FF_DIM, FF_DIM, KP);

    // 7. combine+bias+LN2 -> h_bf
    combine_ln_kernel<6><<<B_ROWS, 256, 0, stream>>>(Pb, bo, g2, b2, h_bf, D_EMB, KP);

    // 8. W1 GEMM: N=6272, Z=2, grid 8x49x2 = 784 blocks, 12-13 iters/block
    gemm_bf16<<<dim3(8, 49, 2), 256, 0, stream>>>(h_bf, W1t, Pb, FF_DIM, KP, 25);

    // 9. W2^T [896][6272] (after W1 GEMM)
    transpose_plain<<<dim3(14, 98), 256, 0, stream>>>(W2, W2t, FF_DIM, OUT_DIM, 896, FF_DIM);

    // 10. combine Z=2 + bias + GELU -> ff1 (in-place plane 0)
    combine_gelu_kernel<<<dim3(7, B_ROWS), 256, 0, stream>>>(Pb, b1f, FF_DIM);

    // 11. W2 GEMM: N=784, K=6272, Z=9, grid 8x7x9 = 504 blocks, ~11 iters/block
    gemm_bf16<<<dim3(8, 7, 9), 256, 0, stream>>>(ff1, W2t, Pw2, OUT_DIM, FF_DIM, 98);

    // 12. combine Z=9 + bias -> out (fp32)
    combine_out_kernel<9><<<dim3(2, B_ROWS), 256, 0, stream>>>(Pw2, b2f, out, OUT_DIM);
}

// Round 7
// 351.728 us; speedup vs baseline: 1.1008x; 1.0593x over previous
//
#include <hip/hip_runtime.h>
#include <math.h>

#define B_ROWS 1024
#define D_EMB  1568
#define KP     1600      // D_EMB padded to a multiple of 64 (BK)
#define H_HEADS 16
#define HSZ    98
#define FF_DIM 6272
#define OUT_DIM 784

typedef unsigned short ushort_t;
typedef __attribute__((ext_vector_type(8))) short short8;
typedef __attribute__((ext_vector_type(4))) float floatx4;

static __device__ __forceinline__ ushort_t f2bf(float f) {
    unsigned int u = __builtin_bit_cast(unsigned int, f);
    u = (u + 0x7fffu + ((u >> 16) & 1u)) >> 16;   // RNE; our values are never NaN
    return (ushort_t)u;
}
static __device__ __forceinline__ float bf2f(ushort_t h) {
    unsigned int u = ((unsigned int)h) << 16;
    return __builtin_bit_cast(float, u);
}

// async 16B global -> LDS. dest = wave-uniform base; HW scatters lane*16.
static __device__ __forceinline__ void load16_to_lds(const void* g, void* l) {
    __builtin_amdgcn_global_load_lds(
        (const __attribute__((address_space(1))) void*)g,
        (__attribute__((address_space(3))) void*)l,
        16, 0, 0);
}

// ---------------- LayerNorm: fp32 in -> bf16 out (cols D..DPAD zeroed) ----------------
__global__ __launch_bounds__(256) void ln_kernel(const float* __restrict__ x,
                                                 const float* __restrict__ g,
                                                 const float* __restrict__ b,
                                                 ushort_t* __restrict__ out,
                                                 int D, int DPAD) {
    const int row = blockIdx.x;
    const float* xr = x + (size_t)row * D;
    ushort_t* orow = out + (size_t)row * DPAD;

    float s = 0.f, s2 = 0.f;
    for (int i = threadIdx.x; i < D; i += blockDim.x) {
        float v = xr[i];
        s += v; s2 += v * v;
    }
    #pragma unroll
    for (int off = 32; off > 0; off >>= 1) {
        s  += __shfl_down(s,  off, 64);
        s2 += __shfl_down(s2, off, 64);
    }
    __shared__ float ws_[8], ws2_[8];
    const int wave = threadIdx.x >> 6, lane = threadIdx.x & 63;
    if (lane == 0) { ws_[wave] = s; ws2_[wave] = s2; }
    __syncthreads();
    if (threadIdx.x == 0) {
        float ts = 0.f, ts2 = 0.f;
        for (int i = 0; i < 4; i++) { ts += ws_[i]; ts2 += ws2_[i]; }
        ws_[0] = ts; ws2_[0] = ts2;
    }
    __syncthreads();
    const float mean = ws_[0] / (float)D;
    const float var  = ws2_[0] / (float)D - mean * mean;
    const float inv  = rsqrtf(var + 1e-5f);
    for (int i = threadIdx.x; i < DPAD; i += blockDim.x)
        orow[i] = (i < D) ? f2bf((xr[i] - mean) * inv * g[i] + b[i]) : (ushort_t)0;
}

// ---------------- 64x64 transpose tile worker ----------------
// src fp32 [Kvalid][srcN] (reads rows k0.., cols n0..). dst bf16 row (dbase+n), col k,
// row-stride dstride. Rows n in [Nvalid, Npad) get zeros. Kvalid % 4 == 0.
static __device__ __forceinline__ void transpose_tile(const float* __restrict__ src,
                                                      ushort_t* __restrict__ dst,
                                                      int srcN, int Kvalid,
                                                      int k0, int n0,
                                                      int Nvalid, int Npad,
                                                      int dstride, int dbase) {
    __shared__ float t[64][65];
    const int tid = threadIdx.x;
    const int tx = tid & 63, ty = tid >> 6;
    #pragma unroll
    for (int r = 0; r < 16; r++) {
        const int kl = ty + r * 4;
        const int k = k0 + kl, n = n0 + tx;
        t[tx][kl] = (k < Kvalid && n < Nvalid) ? src[(size_t)k * srcN + n] : 0.f;
    }
    __syncthreads();
    #pragma unroll
    for (int w = 0; w < 4; w++) {
        const int nl = (tid >> 4) + w * 16;
        const int kc = (tid & 15) * 4;
        const int n = n0 + nl, k = k0 + kc;
        if (n < Npad && k < Kvalid) {       // Kvalid%4==0: whole quad in-bounds
            ushort4 uv;
            uv.x = f2bf(t[nl][kc + 0]);
            uv.y = f2bf(t[nl][kc + 1]);
            uv.z = f2bf(t[nl][kc + 2]);
            uv.w = f2bf(t[nl][kc + 3]);
            *(ushort4*)(dst + (size_t)(dbase + n) * dstride + k) = uv;
        }
    }
}

// prep1: Wq/Wk/Wv (H,1568,98) -> qkvt [4736][KP] rows which*1568+head*98+e;
//        Wo (1568,1568) -> Wot [1664][KP].  Grid = 2400 + 650 = 3050 blocks.
__global__ __launch_bounds__(256) void prep1_kernel(const float* __restrict__ Wq,
                                                    const float* __restrict__ Wk,
                                                    const float* __restrict__ Wv,
                                                    const float* __restrict__ Wo,
                                                    ushort_t* __restrict__ qkvt,
                                                    ushort_t* __restrict__ Wot) {
    const int id = blockIdx.x;
    if (id < 2400) {                       // qkv tiles
        const int ktile = id % 25;
        const int rest  = id / 25;
        const int ntile = rest & 1;
        const int hw    = rest >> 1;
        const int head  = hw & 15;
        const int which = hw >> 4;
        const float* src = (which == 0) ? Wq : (which == 1) ? Wk : Wv;
        src += (size_t)head * D_EMB * HSZ;
        transpose_tile(src, qkvt, HSZ, D_EMB, ktile * 64, ntile * 64,
                       HSZ, HSZ, KP, which * D_EMB + head * HSZ);
    } else {                               // Wo tiles: 26 n-tiles x 25 k-tiles
        const int id2 = id - 2400;
        const int ktile = id2 % 25;
        const int ntile = id2 / 25;
        transpose_tile(Wo, Wot, D_EMB, D_EMB, ktile * 64, ntile * 64,
                       D_EMB, 1664, KP, 0);
    }
}

// prep2: W1 (1568,6272) -> W1t [6272][KP]; W2 (6272,784) -> W2t [896][6272].
// Grid = 2450 + 1372 = 3822 blocks.
__global__ __launch_bounds__(256) void prep2_kernel(const float* __restrict__ W1,
                                                    const float* __restrict__ W2,
                                                    ushort_t* __restrict__ W1t,
                                                    ushort_t* __restrict__ W2t) {
    const int id = blockIdx.x;
    if (id < 2450) {                       // W1: 98 n-tiles x 25 k-tiles
        const int ktile = id % 25;
        const int ntile = id / 25;
        transpose_tile(W1, W1t, FF_DIM, D_EMB, ktile * 64, ntile * 64,
                       FF_DIM, FF_DIM, KP, 0);
    } else {                               // W2: 14 n-tiles x 98 k-tiles
        const int id2 = id - 2450;
        const int ktile = id2 % 98;
        const int ntile = id2 / 98;
        transpose_tile(W2, W2t, OUT_DIM, FF_DIM, ktile * 64, ntile * 64,
                       OUT_DIM, 896, FF_DIM, 0);
    }
}

// -------- bf16 MFMA GEMM, 128x128 tile, BK=64 (two 32-k panels per barrier) --------
// A: bf16 [1024][Kstride] row-major (k-pad zeroed).  Bt: bf16 [Npad][Kstride] k-major.
// EPI 0: split-K bf16 plane P[z][1024][N].  EPI 1: bias + exact GELU -> bf16 direct (z=1).
template <int EPI>
__global__ __launch_bounds__(256) void gemm_bf16(const ushort_t* __restrict__ A,
                                                 const ushort_t* __restrict__ Bt,
                                                 ushort_t* __restrict__ P,
                                                 const float* __restrict__ bias,
                                                 int N, int Kstride, int nkTot) {
    __shared__ __align__(16) ushort_t As[2 * 128 * 32];   // [ks][row][32]
    __shared__ __align__(16) ushort_t Bs[2 * 128 * 32];

    const int tid  = threadIdx.x;
    const int wave = tid >> 6, lane = tid & 63;
    const int quad = lane >> 4, l16 = lane & 15;
    const int m0 = blockIdx.x * 128;
    const int n0 = blockIdx.y * 128;
    const int z = blockIdx.z, Z = gridDim.z;
    const int it0 = (int)((long long)nkTot * z / Z);
    const int it1 = (int)((long long)nkTot * (z + 1) / Z);

    const int srow = lane >> 2;          // 0..15
    const int scol = (lane & 3) << 3;    // 0,8,16,24
    const int wm = wave & 1, wn = wave >> 1;

    floatx4 acc[4][4] = {};

    for (int it = it0; it < it1; ++it) {
        const int k0 = it << 6;
        #pragma unroll
        for (int c = 0; c < 2; ++c) {
            const int rg = wave * 2 + c;             // wave-uniform rowgroup
            const int row = rg * 16 + srow;
            #pragma unroll
            for (int ks = 0; ks < 2; ++ks) {
                load16_to_lds(A  + (size_t)(m0 + row) * Kstride + k0 + ks * 32 + scol,
                              &As[ks * 4096 + rg * 512]);
                load16_to_lds(Bt + (size_t)(n0 + row) * Kstride + k0 + ks * 32 + scol,
                              &Bs[ks * 4096 + rg * 512]);
            }
        }
        __syncthreads();

        #pragma unroll
        for (int ks = 0; ks < 2; ++ks) {
            short8 af[4], bfr[4];
            #pragma unroll
            for (int i = 0; i < 4; i++)
                af[i] = *(const short8*)&As[ks * 4096 + (wm * 64 + i * 16 + l16) * 32 + quad * 8];
            #pragma unroll
            for (int j = 0; j < 4; j++)
                bfr[j] = *(const short8*)&Bs[ks * 4096 + (wn * 64 + j * 16 + l16) * 32 + quad * 8];
            #pragma unroll
            for (int i = 0; i < 4; i++)
                #pragma unroll
                for (int j = 0; j < 4; j++)
                    acc[i][j] = __builtin_amdgcn_mfma_f32_16x16x32_bf16(af[i], bfr[j], acc[i][j], 0, 0, 0);
        }
        __syncthreads();
    }

    ushort_t* Pz = (EPI == 0) ? (P + (size_t)z * B_ROWS * N) : P;
    #pragma unroll
    for (int i = 0; i < 4; i++) {
        const int rbase = m0 + wm * 64 + i * 16 + quad * 4;
        #pragma unroll
        for (int j = 0; j < 4; j++) {
            const int col = n0 + wn * 64 + j * 16 + l16;
            if (col < N) {
                #pragma unroll
                for (int r = 0; r < 4; r++) {
                    float v = acc[i][j][r];
                    if (EPI == 1) {
                        v += bias[col];
                        v = 0.5f * v * (1.f + erff(v * 0.70710678118654752f));
                    }
                    Pz[(size_t)(rbase + r) * N + col] = f2bf(v);
                }
            }
        }
    }
}

// -------- fused: Z-plane combine + bias + LayerNorm -> bf16 [1024][NPAD], pad zeroed --------
template <int Z>
__global__ __launch_bounds__(256) void combine_ln_kernel(const ushort_t* __restrict__ P,
                                                         const float* __restrict__ bias,
                                                         const float* __restrict__ g,
                                                         const float* __restrict__ b,
                                                         ushort_t* __restrict__ out,
                                                         int N, int NPAD) {
    __shared__ float t[D_EMB];
    __shared__ float ws_[8], ws2_[8];
    const int row = blockIdx.x;
    const size_t plane = (size_t)B_ROWS * N;
    const ushort_t* Pr = P + (size_t)row * N;
    const int half = N >> 1;

    float s = 0.f, s2 = 0.f;
    for (int i = threadIdx.x; i < half; i += blockDim.x) {
        float v0 = bias[2 * i], v1 = bias[2 * i + 1];
        #pragma unroll
        for (int zz = 0; zz < Z; zz++) {
            const ushort2 u = *(const ushort2*)(Pr + (size_t)zz * plane + 2 * i);
            v0 += bf2f(u.x); v1 += bf2f(u.y);
        }
        t[2 * i] = v0; t[2 * i + 1] = v1;
        s += v0 + v1; s2 += v0 * v0 + v1 * v1;
    }
    #pragma unroll
    for (int off = 32; off > 0; off >>= 1) {
        s  += __shfl_down(s,  off, 64);
        s2 += __shfl_down(s2, off, 64);
    }
    const int wave = threadIdx.x >> 6, lane = threadIdx.x & 63;
    if (lane == 0) { ws_[wave] = s; ws2_[wave] = s2; }
    __syncthreads();
    if (threadIdx.x == 0) {
        float ts = 0.f, ts2 = 0.f;
        for (int i = 0; i < 4; i++) { ts += ws_[i]; ts2 += ws2_[i]; }
        ws_[0] = ts; ws2_[0] = ts2;
    }
    __syncthreads();
    const float mean = ws_[0] / (float)N;
    const float var  = ws2_[0] / (float)N - mean * mean;
    const float inv  = rsqrtf(var + 1e-5f);
    ushort_t* orow = out + (size_t)row * NPAD;
    for (int i = threadIdx.x; i < NPAD; i += blockDim.x)
        orow[i] = (i < N) ? f2bf((t[i] - mean) * inv * g[i] + b[i]) : (ushort_t)0;
}

// -------- combine Z planes + bias -> fp32 out --------
template <int Z>
__global__ __launch_bounds__(256) void combine_out_kernel(const ushort_t* __restrict__ P,
                                                          const float* __restrict__ bias,
                                                          float* __restrict__ out, int N) {
    const int c2 = blockIdx.x * 256 + threadIdx.x;
    if (c2 >= (N >> 1)) return;
    const int row = blockIdx.y;
    const size_t plane = (size_t)B_ROWS * N;
    const size_t off = (size_t)row * N + 2 * c2;
    float v0 = bias[2 * c2], v1 = bias[2 * c2 + 1];
    #pragma unroll
    for (int zz = 0; zz < Z; zz++) {
        const ushort2 u = *(const ushort2*)(P + (size_t)zz * plane + off);
        v0 += bf2f(u.x); v1 += bf2f(u.y);
    }
    out[off] = v0; out[off + 1] = v1;
}

// ---------------- rank-1 pseudo-attention (sums the 2 QKV partial planes inline) ----------------
// P: 2 bf16 planes [1024][4704]: q at col h*98+e, k at +1568, v at +3136. out bf16 [1024][KP].
__global__ __launch_bounds__(128) void attn_kernel(const ushort_t* __restrict__ P,
                                                   ushort_t* __restrict__ out) {
    const int bh = blockIdx.x;
    const int b = bh >> 4, h = bh & 15;
    const size_t base = (size_t)b * 4704 + h * HSZ;
    const size_t plane = (size_t)B_ROWS * 4704;

    __shared__ float ks[HSZ], vs[HSZ];
    __shared__ float kmax_s, kmin_s;

    const int t = threadIdx.x;
    if (t < HSZ) {
        ks[t] = bf2f(P[base + 1568 + t]) + bf2f(P[plane + base + 1568 + t]);
        vs[t] = bf2f(P[base + 3136 + t]) + bf2f(P[plane + base + 3136 + t]);
    }
    __syncthreads();
    if (t == 0) {
        float mx = -1e30f, mn = 1e30f;
        for (int j = 0; j < HSZ; j++) { mx = fmaxf(mx, ks[j]); mn = fminf(mn, ks[j]); }
        kmax_s = mx; kmin_s = mn;
    }
    __syncthreads();
    if (t < HSZ) {
        const float q = bf2f(P[base + t]) + bf2f(P[plane + base + t]);
        const float ti = q * 0.025253813613805268f;  // 1568^-0.5
        const float m = (ti >= 0.f) ? ti * kmax_s : ti * kmin_s;
        float s = 0.f, acc = 0.f;
        for (int j = 0; j < HSZ; j++) {
            const float e = __expf(ti * ks[j] - m);
            s += e; acc += e * vs[j];
        }
        out[(size_t)b * KP + h * HSZ + t] = f2bf(acc / s);
    }
}

// ---------------- launch ----------------
// Workspace map (peak 51,052,544 B <= 51,380,224 proven-safe). Serial liveness:
//   A [0, 20,480,000):  qkvt [0,15,155,200) + Wot [15,155,200,20,480,000)
//                       -> W1t [0,20,070,400) after Wo GEMM (prep2 runs post-combine_ln)
//                       -> P_W2 Z=9 [0,14,450,688) after W1 GEMM
//   P [20,480,000, 47,775,744): P_qkv Z=2 (19.27MB) -> P_Wo Z=4 (12.85MB)
//                       -> ff1 [20,480,000,33,325,056) + W2t [33,325,056,44,564,480)
//   C [47,775,744, 51,052,544): h_bf [1024][KP] bf16 (LN1 -> attn -> LN2, serial)
extern "C" void kernel_launch(void* const* d_in, const int* in_sizes, int n_in,
                              void* d_out, int out_size, void* d_ws, size_t ws_size,
                              hipStream_t stream) {
    const float* x   = (const float*)d_in[0];
    const float* Wq  = (const float*)d_in[1];
    const float* Wk  = (const float*)d_in[2];
    const float* Wv  = (const float*)d_in[3];
    const float* Wo  = (const float*)d_in[4];
    const float* bo  = (const float*)d_in[5];
    const float* g1  = (const float*)d_in[6];
    const float* b1  = (const float*)d_in[7];
    const float* g2  = (const float*)d_in[8];
    const float* b2  = (const float*)d_in[9];
    const float* W1  = (const float*)d_in[10];
    const float* b1f = (const float*)d_in[11];
    const float* W2  = (const float*)d_in[12];
    const float* b2f = (const float*)d_in[13];
    float* out = (float*)d_out;

    char* w = (char*)d_ws;
    ushort_t* qkvt = (ushort_t*)(w);
    ushort_t* Wot  = (ushort_t*)(w + 15155200);
    ushort_t* W1t  = (ushort_t*)(w);
    ushort_t* Pw2  = (ushort_t*)(w);                // W2 partials Z=9 (region A, post-W1)
    ushort_t* Pb   = (ushort_t*)(w + 20480000);     // P_qkv / P_Wo planes
    ushort_t* ff1  = (ushort_t*)(w + 20480000);     // W1 output (planes dead)
    ushort_t* W2t  = (ushort_t*)(w + 33325056);
    ushort_t* h_bf = (ushort_t*)(w + 47775744);     // serial LN1/attn/LN2 buffer [1024][KP]

    // 1. LN1 -> h_bf (pad cols zeroed)
    ln_kernel<<<B_ROWS, 256, 0, stream>>>(x, g1, b1, h_bf, D_EMB, KP);

    // 2. prep1: Wqkv^T + Wo^T (one dispatch, 3050 tiles)
    prep1_kernel<<<3050, 256, 0, stream>>>(Wq, Wk, Wv, Wo, qkvt, Wot);

    // 3. QKV GEMM: N=4704, Z=2, grid 8x37x2 = 592 blocks
    gemm_bf16<0><<<dim3(8, 37, 2), 256, 0, stream>>>(h_bf, qkvt, Pb, nullptr, 4704, KP, 25);

    // 4. attention (sums 2 planes) -> h_bf
    attn_kernel<<<B_ROWS * H_HEADS, 128, 0, stream>>>(Pb, h_bf);

    // 5. Wo GEMM: N=1568, Z=4, grid 8x13x4 = 416 blocks
    gemm_bf16<0><<<dim3(8, 13, 4), 256, 0, stream>>>(h_bf, Wot, Pb, nullptr, D_EMB, KP, 25);

    // 6. combine+bias+LN2 -> h_bf
    combine_ln_kernel<4><<<B_ROWS, 256, 0, stream>>>(Pb, bo, g2, b2, h_bf, D_EMB, KP);

    // 7. prep2: W1^T + W2^T (one dispatch, 3822 tiles; A and P_Wo regions now free)
    prep2_kernel<<<3822, 256, 0, stream>>>(W1, W2, W1t, W2t);

    // 8. W1 GEMM: N=6272, Z=1, fused bias+GELU -> ff1 bf16, grid 8x49 = 392 blocks
    gemm_bf16<1><<<dim3(8, 49, 1), 256, 0, stream>>>(h_bf, W1t, ff1, b1f, FF_DIM, KP, 25);

    // 9. W2 GEMM: N=784, K=6272, Z=9, grid 8x7x9 = 504 blocks -> planes in region A
    gemm_bf16<0><<<dim3(8, 7, 9), 256, 0, stream>>>(ff1, W2t, Pw2, nullptr, OUT_DIM, FF_DIM, 98);

    // 10. combine Z=9 + bias -> out (fp32)
    combine_out_kernel<9><<<dim3(2, B_ROWS), 256, 0, stream>>>(Pw2, b2f, out, OUT_DIM);
}